// Round 9
// baseline (515.051 us; speedup 1.0000x reference)
//
#include <hip/hip_runtime.h>

#define NN 8192
#define NFEAT 512
#define NHID 128
#define NCLASS 16
#define CAP 128
#define K2_BLOCKS (NN / 16)   // 512

// ---------------------------------------------------------------------------
// Fused kernel A: block-range split of two INDEPENDENT ops so the HBM-bound
// adjacency scan overlaps the compute-bound GEMM.
//   blocks [0, NN):            k1 — compact row blockIdx of dense adj,
//                              rowcnt/cols/dinv. (the only 268 MB read)
//   blocks [NN, NN+K2_BLOCKS): k2 — xw = x @ W1, 16 rows per block.
// ---------------------------------------------------------------------------
__global__ __launch_bounds__(256) void kA(const float* __restrict__ adj,
                                          const float* __restrict__ x,
                                          const float* __restrict__ W1,
                                          int* __restrict__ rowcnt,
                                          int* __restrict__ cols,
                                          float* __restrict__ dinv,
                                          float* __restrict__ xw) {
  if (blockIdx.x < NN) {
    // ---- k1: adjacency row compaction ----
    int row = blockIdx.x;
    __shared__ int cnt;
    if (threadIdx.x == 0) cnt = 0;
    __syncthreads();
    const float4* arow = (const float4*)(adj + (size_t)row * NN);
    int* crow = cols + (size_t)row * CAP;
    float4 v[8];
#pragma unroll
    for (int u = 0; u < 8; ++u) v[u] = arow[threadIdx.x + 256 * u];  // all loads in flight
#pragma unroll
    for (int u = 0; u < 8; ++u) {
      int j0 = (threadIdx.x + 256 * u) * 4;
      if (v[u].x != 0.0f) { int s = atomicAdd(&cnt, 1); if (s < CAP) crow[s] = j0; }
      if (v[u].y != 0.0f) { int s = atomicAdd(&cnt, 1); if (s < CAP) crow[s] = j0 + 1; }
      if (v[u].z != 0.0f) { int s = atomicAdd(&cnt, 1); if (s < CAP) crow[s] = j0 + 2; }
      if (v[u].w != 0.0f) { int s = atomicAdd(&cnt, 1); if (s < CAP) crow[s] = j0 + 3; }
    }
    __syncthreads();
    if (threadIdx.x == 0) {
      rowcnt[row] = min(cnt, CAP);
      dinv[row] = rsqrtf((float)cnt + 1.0f);
    }
  } else {
    // ---- k2: xw = x @ W1 ----
    int blk = blockIdx.x - NN;
    int p = threadIdx.x & 127;
    int g = threadIdx.x >> 7;                 // 0..1
    int rbase = blk * 16 + g * 8;
    const float* xr0 = x + (size_t)rbase * NFEAT;
    float acc[8] = {};
    for (int k = 0; k < NFEAT; k += 4) {
      float4 xv[8];
#pragma unroll
      for (int r = 0; r < 8; ++r)
        xv[r] = *(const float4*)(xr0 + (size_t)r * NFEAT + k);
#pragma unroll
      for (int t = 0; t < 4; ++t) {
        float w = W1[(size_t)(k + t) * NHID + p];
#pragma unroll
        for (int r = 0; r < 8; ++r) {
          float xe = (t == 0) ? xv[r].x : (t == 1) ? xv[r].y
                   : (t == 2) ? xv[r].z : xv[r].w;
          acc[r] = fmaf(xe, w, acc[r]);
        }
      }
    }
#pragma unroll
    for (int r = 0; r < 8; ++r)
      xw[(size_t)(rbase + r) * NHID + p] = acc[r];
  }
}

// ---------------------------------------------------------------------------
// Kernel B (fused gc1+relu+gc2-matmul): h_row = relu(A_norm @ xw + b1) in LDS,
// then hw_row = h_row @ W2 via per-block partial reduction. Block = one row.
// ---------------------------------------------------------------------------
__global__ __launch_bounds__(128) void kB(const float* __restrict__ xw,
                                          const int* __restrict__ rowcnt,
                                          const int* __restrict__ cols,
                                          const float* __restrict__ dinv,
                                          const float* __restrict__ b1,
                                          const float* __restrict__ W2,
                                          float* __restrict__ hw) {
  __shared__ int   sj[CAP];
  __shared__ float sw[CAP];
  __shared__ float sh[NHID];
  __shared__ float part[128];
  int row = blockIdx.x;
  int c = threadIdx.x;
  int cnt = rowcnt[row];
  const int* crow = cols + (size_t)row * CAP;
  if (c < cnt) { int j = crow[c]; sj[c] = j; sw[c] = dinv[j]; }
  __syncthreads();
  float di = dinv[row];
  float acc = di * xw[(size_t)row * NHID + c];   // self-loop (I) term
  int e = 0;
  for (; e + 4 <= cnt; e += 4) {
    int j0 = sj[e], j1 = sj[e + 1], j2 = sj[e + 2], j3 = sj[e + 3];
    float w0 = sw[e], w1 = sw[e + 1], w2 = sw[e + 2], w3 = sw[e + 3];
    float v0 = xw[(size_t)j0 * NHID + c];
    float v1 = xw[(size_t)j1 * NHID + c];
    float v2 = xw[(size_t)j2 * NHID + c];
    float v3 = xw[(size_t)j3 * NHID + c];
    acc = fmaf(w0, v0, acc);
    acc = fmaf(w1, v1, acc);
    acc = fmaf(w2, v2, acc);
    acc = fmaf(w3, v3, acc);
  }
  for (; e < cnt; ++e) acc = fmaf(sw[e], xw[(size_t)sj[e] * NHID + c], acc);
  float h = fmaxf(fmaf(di, acc, b1[c]), 0.0f);
  sh[c] = h;
  __syncthreads();
  int cc = c & 15, seg = c >> 4;
  float pacc = 0.0f;
#pragma unroll
  for (int kk = 0; kk < 16; ++kk) {
    int k = seg * 16 + kk;
    pacc = fmaf(sh[k], W2[(size_t)k * NCLASS + cc], pacc);
  }
  part[c] = pacc;
  __syncthreads();
  if (c < 16) {
    float s = 0.0f;
#pragma unroll
    for (int sg = 0; sg < 8; ++sg) s += part[c + 16 * sg];
    hw[(size_t)row * NCLASS + c] = s;
  }
}

// ---------------------------------------------------------------------------
// Kernel C: out = log_softmax(A_norm @ hw + b2). One wave per row; 4 edge
// slots x 16 classes per lane; (j,w) register-cached + shfl broadcast.
// ---------------------------------------------------------------------------
__global__ __launch_bounds__(256) void kC(const float* __restrict__ hw,
                                          const int* __restrict__ rowcnt,
                                          const int* __restrict__ cols,
                                          const float* __restrict__ dinv,
                                          const float* __restrict__ b2,
                                          float* __restrict__ out) {
  int lane = threadIdx.x & 63;
  int wid = threadIdx.x >> 6;
  int row = blockIdx.x * 4 + wid;
  int cnt = rowcnt[row];
  const int* crow = cols + (size_t)row * CAP;
  int jA = 0; float wA = 0.0f;
  if (lane < cnt) { jA = crow[lane]; wA = dinv[jA]; }
  int jB = 0; float wB = 0.0f;
  if (lane + 64 < cnt) { jB = crow[lane + 64]; wB = dinv[jB]; }
  int c = lane & 15, slot = lane >> 4;
  float acc = 0.0f;
  for (int e0 = 0; e0 < cnt; e0 += 4) {
    int e = e0 + slot;
    int   j1 = __shfl(jA, e & 63);
    float w1 = __shfl(wA, e & 63);
    int   j2 = __shfl(jB, (e - 64) & 63);
    float w2 = __shfl(wB, (e - 64) & 63);
    int   j = (e < 64) ? j1 : j2;
    float w = (e < 64) ? w1 : w2;
    if (e < cnt) acc = fmaf(w, hw[(size_t)j * NCLASS + c], acc);
  }
  acc += __shfl_xor(acc, 16);
  acc += __shfl_xor(acc, 32);
  float di = dinv[row];
  float self = hw[(size_t)row * NCLASS + c];
  float v = fmaf(di, acc, fmaf(di * di, self, b2[c]));
  float m = v;
#pragma unroll
  for (int o = 8; o >= 1; o >>= 1) m = fmaxf(m, __shfl_xor(m, o, 16));
  float ex = __expf(v - m);
  float s = ex;
#pragma unroll
  for (int o = 8; o >= 1; o >>= 1) s += __shfl_xor(s, o, 16);
  if (slot == 0) out[(size_t)row * NCLASS + c] = v - m - logf(s);
}

// ---------------------------------------------------------------------------

extern "C" void kernel_launch(void* const* d_in, const int* in_sizes, int n_in,
                              void* d_out, int out_size, void* d_ws, size_t ws_size,
                              hipStream_t stream) {
  const float* x   = (const float*)d_in[0];
  const float* adj = (const float*)d_in[1];
  const float* W1  = (const float*)d_in[2];
  const float* b1  = (const float*)d_in[3];
  const float* W2  = (const float*)d_in[4];
  const float* b2  = (const float*)d_in[5];
  float* out = (float*)d_out;

  char* ws = (char*)d_ws;
  float* dinv = (float*)(ws);                      // 32 KB
  int*   rowc = (int*)(ws + 32768);                // 32 KB
  int*   cols = (int*)(ws + 65536);                // 4 MB
  float* xw   = (float*)(ws + 65536 + 4194304);    // 4 MB
  float* hw   = (float*)(ws + 65536 + 8388608);    // 512 KB

  kA<<<NN + K2_BLOCKS, 256, 0, stream>>>(adj, x, W1, rowc, cols, dinv, xw);
  kB<<<NN, 128, 0, stream>>>(xw, rowc, cols, dinv, b1, W2, hw);
  kC<<<NN / 4, 256, 0, stream>>>(hw, rowc, cols, dinv, b2, out);
}